// Round 1
// baseline (349.097 us; speedup 1.0000x reference)
//
#include <hip/hip_runtime.h>
#include <math.h>
#include <stdint.h>

#define N_NODES 32768
#define E_DIM   512
#define H_HEADS 8
#define D_HEAD  64
#define NNZ_E   524288

typedef __attribute__((ext_vector_type(4))) float f32x4;
typedef __attribute__((ext_vector_type(8))) short bf16x8;  // 8 bf16 = 4 VGPRs
typedef __attribute__((ext_vector_type(8))) short s16x8;

__device__ __forceinline__ unsigned short f32_to_bf16_rne(float f) {
  union { float f; uint32_t u; } v; v.f = f;
  const uint32_t u = v.u;
  return (unsigned short)((u + 0x7FFFu + ((u >> 16) & 1u)) >> 16);
}
__device__ __forceinline__ float bf16_to_f32(unsigned short h) {
  union { uint32_t u; float f; } v; v.u = ((uint32_t)h) << 16;
  return v.f;
}

// async 16B global->LDS (wave-uniform LDS base + lane*16)
__device__ __forceinline__ void async16(const void* g, void* l) {
  __builtin_amdgcn_global_load_lds(
      (const __attribute__((address_space(1))) void*)g,
      (__attribute__((address_space(3))) void*)l, 16, 0, 0);
}

// split pair (a,b) fp32 -> packed bf16 hi dword + packed bf16 lo dword.
__device__ __forceinline__ void split2(float a, float b,
                                       uint32_t& hi, uint32_t& lo) {
  const uint32_t ua = __float_as_uint(a), ub = __float_as_uint(b);
  hi = __builtin_amdgcn_perm(ub, ua, 0x07060302u);  // [b.hi16 : a.hi16]
  const float ra = a - __uint_as_float(ua & 0xFFFF0000u);
  const float rb = b - __uint_as_float(ub & 0xFFFF0000u);
  lo = __builtin_amdgcn_perm(__float_as_uint(rb), __float_as_uint(ra),
                             0x07060302u);
}

// ---------------------------------------------------------------------------
// prep_small: blocks 0..511 -> cvt_w (split q_w/k_w into bf16 hi|lo);
//             blocks 512..2559 -> build_aux (ge + CSR row_start).
// ---------------------------------------------------------------------------
__global__ __launch_bounds__(256) void prep_small(
    const float* __restrict__ q_w, const float* __restrict__ k_w,
    const int* __restrict__ row_index, const int* __restrict__ col_index,
    const int* __restrict__ to_col,
    unsigned short* __restrict__ wq_s, unsigned short* __restrict__ wk_s,
    int* __restrict__ row_start, int* __restrict__ ge) {
  const int b = blockIdx.x;
  if (b < 512) {
    const float* src = (b < 256) ? q_w : k_w;
    unsigned short* dst = (b < 256) ? wq_s : wk_s;
    const int t = (b & 255) * 256 + threadIdx.x;
    const int r = t >> 7;
    const int c4 = (t & 127) << 2;
    const float4 v = *(const float4*)(src + (size_t)r * 512 + c4);
    ushort4 hi, lo;
    hi.x = f32_to_bf16_rne(v.x); lo.x = f32_to_bf16_rne(v.x - bf16_to_f32(hi.x));
    hi.y = f32_to_bf16_rne(v.y); lo.y = f32_to_bf16_rne(v.y - bf16_to_f32(hi.y));
    hi.z = f32_to_bf16_rne(v.z); lo.z = f32_to_bf16_rne(v.z - bf16_to_f32(hi.z));
    hi.w = f32_to_bf16_rne(v.w); lo.w = f32_to_bf16_rne(v.w - bf16_to_f32(hi.w));
    *(ushort4*)(dst + (size_t)r * 1024 + c4) = hi;
    *(ushort4*)(dst + (size_t)r * 1024 + 512 + c4) = lo;
  } else {
    const int e = (b - 512) * 256 + threadIdx.x;
    if (e < NNZ_E) {
      ge[e] = to_col[col_index[e]];
      const int r0 = row_index[e];
      const int r1 = (e + 1 < NNZ_E) ? row_index[e + 1] : N_NODES;
      if (e == 0)
        for (int r = 0; r <= r0; ++r) row_start[r] = 0;
      for (int r = r0 + 1; r <= r1; ++r) row_start[r] = e + 1;
    }
  }
}

// ---------------------------------------------------------------------------
// Split-bf16 MFMA GEMM, r12 fragment maps + T3-minimum 2-phase pipeline.
// Previous shape (stage -> sync -> compute -> sync) exposed the full
// global_load_lds round-trip (~900 cyc) + two barrier drains per K-step:
// measured 2615 cyc-CU/K-step vs 931 cyc MFMA floor (MfmaUtil 30%).
// Now: double-buffered LDS (64 KiB), stage(k+1) issued BEFORE the
// ds_read+MFMA of k, ONE __syncthreads per K-step (its vmcnt(0)+lgkmcnt(0)
// drain is exactly the handoff both buffers need).
// Hazards: reads of buf[cur] are lgkm-drained at the barrier before the
// next iteration's async stage overwrites it; writes to buf[nxt] are
// vmcnt-drained at the same barrier before compute reads it.
// XCD swizzle (b&7 = panel group) keeps the x panel HBM-once.
// Outputs int16: q16 = q*2048 (1/8 head-scale folded at consumer), k16 = k*4096.
// ---------------------------------------------------------------------------
__global__ __launch_bounds__(256) void gemm_mfma(
    const float* __restrict__ x,             // [N][512] fp32
    const unsigned short* __restrict__ wqs,  // [512][1024] hi|lo
    const unsigned short* __restrict__ wks,
    const float* __restrict__ q_b, const float* __restrict__ k_b,
    short* __restrict__ q16, short* __restrict__ k16) {
  __shared__ float Af[2][128 * 32];          // 2 x 16 KB fp32 A tile
  __shared__ unsigned short Bh[2][128 * 32]; // 2 x 8 KB
  __shared__ unsigned short Bl[2][128 * 32]; // 2 x 8 KB
  const int tid = threadIdx.x;
  const int w = tid >> 6;        // wave 0..3
  const int l = tid & 63;

  const int b = blockIdx.x;
  const int j = b >> 3;
  const int mb = (b & 7) * 32 + (j >> 3);
  const int c = j & 7;
  const bool is_q = ((c & 1) == 0);
  const int bm = mb * 128;
  const int bn = (c >> 1) * 128;

  const unsigned short* __restrict__ wmat = is_q ? wqs : wks;
  const float* __restrict__ bias = is_q ? q_b : k_b;
  short* __restrict__ outp = is_q ? q16 : k16;
  const float oscale = is_q ? 2048.f : 4096.f;

  const int wm = (w & 1) * 64;   // wave's m-quadrant
  const int wn = (w >> 1) * 64;  // wave's n-quadrant

  f32x4 acc[4][4];
#pragma unroll
  for (int i = 0; i < 4; ++i)
#pragma unroll
    for (int jj = 0; jj < 4; ++jj) acc[i][jj] = (f32x4){0.f, 0.f, 0.f, 0.f};

  // A staging (fp32): lds chunk jx of row r holds global chunk jx^(r&7)
  const int ar = l >> 3;
  const int agc = (l & 7) ^ ar;
  // B staging (bf16 hi|lo, r7 swizzle)
  const int sr0 = w * 16 + (l >> 2);
  const int sr1 = sr0 + 64;
  const int sc = (((l & 3) ^ ((l >> 3) & 3)) << 3);
  // fragment maps
  const int fr = l & 15;
  const int fcs = ((((l >> 4) ^ ((fr >> 1) & 3)) & 3) << 3);
  const int akc = (l >> 4) * 2;
  const int as = l & 7;

  const unsigned short* __restrict__ wa = wmat + (size_t)bn * 1024;

  // issue the 8 async16 staging loads for K-step at column k0 into buffer bf
  auto stage = [&](int k0, int bf) {
#pragma unroll
    for (int cc = 0; cc < 4; ++cc) {
      const int rbase = cc * 32 + w * 8;
      async16(x + (size_t)(bm + rbase + ar) * 512 + k0 + agc * 4,
              Af[bf] + rbase * 32);
    }
    async16(wa + (size_t)sr0 * 1024 + k0 + sc, Bh[bf] + w * 512);
    async16(wa + (size_t)sr1 * 1024 + k0 + sc, Bh[bf] + (w + 4) * 512);
    async16(wa + (size_t)sr0 * 1024 + 512 + k0 + sc, Bl[bf] + w * 512);
    async16(wa + (size_t)sr1 * 1024 + 512 + k0 + sc, Bl[bf] + (w + 4) * 512);
  };

  // prologue: stage K-step 0 into buffer 0
  stage(0, 0);
  __syncthreads();

  for (int ks = 0; ks < 16; ++ks) {
    const int cur = ks & 1;
    // prefetch next K-step into the other buffer BEFORE touching LDS/MFMA:
    // the ~900-cyc load latency hides under this step's 48 MFMA.
    if (ks != 15) stage((ks + 1) * 32, cur ^ 1);

    const float* __restrict__ Ac = Af[cur];
    const unsigned short* __restrict__ Bhc = Bh[cur];
    const unsigned short* __restrict__ Blc = Bl[cur];

    bf16x8 ahi[4], alo[4], bh[4];
#pragma unroll
    for (int i = 0; i < 4; ++i) {
      const int row = wm + i * 16 + fr;
      const float* rp = Ac + row * 32;
      const float4 fa = *(const float4*)(rp + ((akc ^ as) << 2));
      const float4 fb = *(const float4*)(rp + (((akc + 1) ^ as) << 2));
      union { uint32_t u[4]; bf16x8 v; } ph, pl;
      split2(fa.x, fa.y, ph.u[0], pl.u[0]);
      split2(fa.z, fa.w, ph.u[1], pl.u[1]);
      split2(fb.x, fb.y, ph.u[2], pl.u[2]);
      split2(fb.z, fb.w, ph.u[3], pl.u[3]);
      ahi[i] = ph.v;
      alo[i] = pl.v;
    }
#pragma unroll
    for (int i = 0; i < 4; ++i)
      bh[i] = *(const bf16x8*)(Bhc + (wn + i * 16 + fr) * 32 + fcs);
#pragma unroll
    for (int i = 0; i < 4; ++i)
#pragma unroll
      for (int jj = 0; jj < 4; ++jj)
        acc[i][jj] = __builtin_amdgcn_mfma_f32_16x16x32_bf16(
            ahi[i], bh[jj], acc[i][jj], 0, 0, 0);
#pragma unroll
    for (int i = 0; i < 4; ++i)
#pragma unroll
      for (int jj = 0; jj < 4; ++jj)
        acc[i][jj] = __builtin_amdgcn_mfma_f32_16x16x32_bf16(
            alo[i], bh[jj], acc[i][jj], 0, 0, 0);
#pragma unroll
    for (int jj = 0; jj < 4; ++jj)
      bh[jj] = *(const bf16x8*)(Blc + (wn + jj * 16 + fr) * 32 + fcs);
#pragma unroll
    for (int i = 0; i < 4; ++i)
#pragma unroll
      for (int jj = 0; jj < 4; ++jj)
        acc[i][jj] = __builtin_amdgcn_mfma_f32_16x16x32_bf16(
            ahi[i], bh[jj], acc[i][jj], 0, 0, 0);

    // single barrier per K-step: drains this step's lds reads (so next
    // stage may overwrite buf[cur]) and the prefetch vmcnt (so next
    // compute may read buf[cur^1]).
    __syncthreads();
  }

  // epilogue: C/D layout col = l&15 (n), row = (l>>4)*4 + reg (m); int16 out
  const int cn = l & 15;
  const int cm4 = (l >> 4) * 4;
  float bvals[4];
#pragma unroll
  for (int jj = 0; jj < 4; ++jj) bvals[jj] = bias[bn + wn + jj * 16 + cn];
#pragma unroll
  for (int i = 0; i < 4; ++i) {
#pragma unroll
    for (int r = 0; r < 4; ++r) {
      const int m = bm + wm + i * 16 + cm4 + r;
      short* op = outp + (size_t)m * 512 + bn + wn + cn;
#pragma unroll
      for (int jj = 0; jj < 4; ++jj) {
        float v = (acc[i][jj][r] + bvals[jj]) * oscale;
        v = fmaxf(fminf(v, 32767.f), -32767.f);
        op[jj * 16] = (short)__float2int_rn(v);
      }
    }
  }
}

// ---------------------------------------------------------------------------
// Phase A: 4 edges per wave, batched loads; q AND k gathered as int16.
// logit = (sum q16*k16) / 2^26 + bias.
// ---------------------------------------------------------------------------
__global__ __launch_bounds__(256) void edge_logits(
    const short* __restrict__ q16, const short* __restrict__ k16,
    const int* __restrict__ row_index, const int* __restrict__ ge,
    const float* __restrict__ att_bias, float* __restrict__ logits) {
  const int wave = threadIdx.x >> 6;
  const int lane = threadIdx.x & 63;
  const int e0 = __builtin_amdgcn_readfirstlane((blockIdx.x * 4 + wave) * 4);

  int r[4], g[4];
#pragma unroll
  for (int i = 0; i < 4; ++i) {
    r[i] = row_index[e0 + i];
    g[i] = ge[e0 + i];
  }

  const int lo = lane * 8;
  s16x8 kv[4], qv[4];
#pragma unroll
  for (int i = 0; i < 4; ++i)
    kv[i] = *(const s16x8*)(k16 + (size_t)g[i] * E_DIM + lo);
#pragma unroll
  for (int i = 0; i < 4; ++i)
    qv[i] = *(const s16x8*)(q16 + (size_t)r[i] * E_DIM + lo);

  const int h = lane >> 3;
#pragma unroll
  for (int i = 0; i < 4; ++i) {
    float s = (float)qv[i][0] * (float)kv[i][0];
    s = fmaf((float)qv[i][1], (float)kv[i][1], s);
    s = fmaf((float)qv[i][2], (float)kv[i][2], s);
    s = fmaf((float)qv[i][3], (float)kv[i][3], s);
    s = fmaf((float)qv[i][4], (float)kv[i][4], s);
    s = fmaf((float)qv[i][5], (float)kv[i][5], s);
    s = fmaf((float)qv[i][6], (float)kv[i][6], s);
    s = fmaf((float)qv[i][7], (float)kv[i][7], s);
    s += __shfl_xor(s, 1);
    s += __shfl_xor(s, 2);
    s += __shfl_xor(s, 4);
    if ((lane & 7) == 0) {
      logits[(size_t)(e0 + i) * H_HEADS + h] =
          s * (1.f / 67108864.f) + att_bias[(size_t)h * NNZ_E + e0 + i];
    }
  }
}

// ---------------------------------------------------------------------------
// Phase B: 4 rows per block (1 wave per row); lane (h,j) strided
// online-softmax + 3-step merge.
// ---------------------------------------------------------------------------
__global__ __launch_bounds__(256) void row_featurize(
    const float* __restrict__ logits, const int* __restrict__ row_start,
    const int* __restrict__ col_index, const float* __restrict__ dist,
    const float* __restrict__ pos, const float* __restrict__ col_pos,
    float* __restrict__ out) {
  const int r = blockIdx.x * 4 + (threadIdx.x >> 6);
  const int lane = threadIdx.x & 63;
  const int h = lane >> 3;
  const int j = lane & 7;
  const int start = row_start[r];
  const int end = row_start[r + 1];

  float m = -INFINITY, l = 0.f, accw = 0.f, a0 = 0.f, a1 = 0.f, a2 = 0.f;

  for (int e = start + j; e < end; e += 8) {
    const float s = logits[(size_t)e * H_HEADS + h];
    const float dd = dist[e];
    const float w = (dd == 0.f) ? 0.f : 1.f / dd;
    const int c = col_index[e];
    const float nm = fmaxf(m, s);
    const float sc = __expf(m - nm);
    const float p = __expf(s - nm);
    m = nm;
    l = fmaf(l, sc, p);
    const float pw = p * w;
    accw = fmaf(accw, sc, pw);
    a0 = fmaf(a0, sc, pw * col_pos[c * 3 + 0]);
    a1 = fmaf(a1, sc, pw * col_pos[c * 3 + 1]);
    a2 = fmaf(a2, sc, pw * col_pos[c * 3 + 2]);
  }

#pragma unroll
  for (int off = 1; off < 8; off <<= 1) {
    const float mo = __shfl_xor(m, off);
    const float lo = __shfl_xor(l, off);
    const float wo = __shfl_xor(accw, off);
    const float b0 = __shfl_xor(a0, off);
    const float b1 = __shfl_xor(a1, off);
    const float b2 = __shfl_xor(a2, off);
    const float nm = fmaxf(m, mo);
    const float s1 = __expf(fmaxf(m - nm, -80.f));  // NaN (inf-inf) -> -80
    const float s2 = __expf(fmaxf(mo - nm, -80.f));
    m = nm;
    l = l * s1 + lo * s2;
    accw = accw * s1 + wo * s2;
    a0 = a0 * s1 + b0 * s2;
    a1 = a1 * s1 + b1 * s2;
    a2 = a2 * s1 + b2 * s2;
  }

  if (j == 0) {
    const float invz = (l > 0.f) ? 1.f / l : 0.f;
    const float avg = accw * invz;
    const float v0 = a0 * invz - avg * pos[r * 3 + 0];
    const float v1 = a1 * invz - avg * pos[r * 3 + 1];
    const float v2 = a2 * invz - avg * pos[r * 3 + 2];
    const float nrm = sqrtf(v0 * v0 + v1 * v1 + v2 * v2);
    const float invn = 1.f / fmaxf(nrm, 1e-12f);
    float4 o;
    o.x = v0 * invn; o.y = v1 * invn; o.z = v2 * invn; o.w = avg;
    *(float4*)(out + (size_t)r * (H_HEADS * 4) + h * 4) = o;
  }
}

// ---------------------------------------------------------------------------
extern "C" void kernel_launch(void* const* d_in, const int* in_sizes, int n_in,
                              void* d_out, int out_size, void* d_ws,
                              size_t ws_size, hipStream_t stream) {
  const float* x        = (const float*)d_in[0];
  const int* row_index  = (const int*)d_in[1];
  const int* col_index  = (const int*)d_in[2];
  const int* to_col     = (const int*)d_in[3];
  const float* att_bias = (const float*)d_in[4];
  const float* dist     = (const float*)d_in[5];
  const float* pos      = (const float*)d_in[6];
  const float* col_pos  = (const float*)d_in[7];
  const float* q_w      = (const float*)d_in[8];
  const float* q_b      = (const float*)d_in[9];
  const float* k_w      = (const float*)d_in[10];
  const float* k_b      = (const float*)d_in[11];
  float* out = (float*)d_out;

  // ws: q16[N*E s16] | k16[N*E s16] | logits[NNZ*H f32] | wq_s | wk_s
  //     | row_start[N+1] | ge[NNZ]
  short* q16 = (short*)d_ws;
  short* k16 = q16 + (size_t)N_NODES * E_DIM;
  float* logits = (float*)(k16 + (size_t)N_NODES * E_DIM);
  unsigned short* wq_s = (unsigned short*)(logits + (size_t)NNZ_E * H_HEADS);
  unsigned short* wk_s = wq_s + 512 * 1024;
  int* row_start = (int*)(wk_s + 512 * 1024);
  int* ge = row_start + (N_NODES + 1);

  prep_small<<<512 + NNZ_E / 256, 256, 0, stream>>>(
      q_w, k_w, row_index, col_index, to_col, wq_s, wk_s, row_start, ge);

  gemm_mfma<<<2048, 256, 0, stream>>>(x, wq_s, wk_s, q_b, k_b, q16, k16);

  edge_logits<<<NNZ_E / 16, 256, 0, stream>>>(q16, k16, row_index, ge,
                                              att_bias, logits);
  row_featurize<<<N_NODES / 4, 256, 0, stream>>>(logits, row_start, col_index,
                                                 dist, pos, col_pos, out);
}

// Round 2
// 341.358 us; speedup vs baseline: 1.0227x; 1.0227x over previous
//
#include <hip/hip_runtime.h>
#include <math.h>
#include <stdint.h>

#define N_NODES 32768
#define E_DIM   512
#define H_HEADS 8
#define D_HEAD  64
#define NNZ_E   524288

typedef __attribute__((ext_vector_type(4))) float f32x4;
typedef __attribute__((ext_vector_type(8))) short bf16x8;  // 8 bf16 = 4 VGPRs
typedef __attribute__((ext_vector_type(8))) short s16x8;

__device__ __forceinline__ unsigned short f32_to_bf16_rne(float f) {
  union { float f; uint32_t u; } v; v.f = f;
  const uint32_t u = v.u;
  return (unsigned short)((u + 0x7FFFu + ((u >> 16) & 1u)) >> 16);
}
__device__ __forceinline__ float bf16_to_f32(unsigned short h) {
  union { uint32_t u; float f; } v; v.u = ((uint32_t)h) << 16;
  return v.f;
}

// async 16B global->LDS (wave-uniform LDS base + lane*16)
__device__ __forceinline__ void async16(const void* g, void* l) {
  __builtin_amdgcn_global_load_lds(
      (const __attribute__((address_space(1))) void*)g,
      (__attribute__((address_space(3))) void*)l, 16, 0, 0);
}

// ---------------------------------------------------------------------------
// prep_small:
//   blocks [0,256)            : split q_w  -> wq_s (bf16 hi|lo, [512][1024])
//   blocks [256,512)          : split k_w  -> wk_s
//   blocks [512,512+16384)    : split x    -> xs   (bf16 hi|lo, [32768][1024])
//   blocks [512+16384, ...)   : ge + CSR row_start
// The x-split hoists ALL split2 VALU work out of the gemm K-loop (it was
// recomputed 16x per element there: 2 waves/block x 8 blocks per x-panel).
// Costs one 128 MB pass here (~25 us), removes ~830 cyc-CU/K-step of VALU
// from the gemm (measured round-0: VALUBusy 32% ~= MFMA stream itself).
// ---------------------------------------------------------------------------
__global__ __launch_bounds__(256) void prep_small(
    const float* __restrict__ x,
    const float* __restrict__ q_w, const float* __restrict__ k_w,
    const int* __restrict__ row_index, const int* __restrict__ col_index,
    const int* __restrict__ to_col,
    unsigned short* __restrict__ wq_s, unsigned short* __restrict__ wk_s,
    unsigned short* __restrict__ xs,
    int* __restrict__ row_start, int* __restrict__ ge) {
  const int b = blockIdx.x;
  if (b < 512 + 16384) {
    const float* src;
    unsigned short* dst;
    int t;
    if (b < 256)      { src = q_w; dst = wq_s; t = b * 256 + threadIdx.x; }
    else if (b < 512) { src = k_w; dst = wk_s; t = (b - 256) * 256 + threadIdx.x; }
    else              { src = x;   dst = xs;   t = (b - 512) * 256 + threadIdx.x; }
    const int r = t >> 7;
    const int c4 = (t & 127) << 2;
    const float4 v = *(const float4*)(src + (size_t)r * 512 + c4);
    ushort4 hi, lo;
    hi.x = f32_to_bf16_rne(v.x); lo.x = f32_to_bf16_rne(v.x - bf16_to_f32(hi.x));
    hi.y = f32_to_bf16_rne(v.y); lo.y = f32_to_bf16_rne(v.y - bf16_to_f32(hi.y));
    hi.z = f32_to_bf16_rne(v.z); lo.z = f32_to_bf16_rne(v.z - bf16_to_f32(hi.z));
    hi.w = f32_to_bf16_rne(v.w); lo.w = f32_to_bf16_rne(v.w - bf16_to_f32(hi.w));
    *(ushort4*)(dst + (size_t)r * 1024 + c4) = hi;
    *(ushort4*)(dst + (size_t)r * 1024 + 512 + c4) = lo;
  } else {
    const int e = (b - 512 - 16384) * 256 + threadIdx.x;
    if (e < NNZ_E) {
      ge[e] = to_col[col_index[e]];
      const int r0 = row_index[e];
      const int r1 = (e + 1 < NNZ_E) ? row_index[e + 1] : N_NODES;
      if (e == 0)
        for (int r = 0; r <= r0; ++r) row_start[r] = 0;
      for (int r = r0 + 1; r <= r1; ++r) row_start[r] = e + 1;
    }
  }
}

// ---------------------------------------------------------------------------
// Split-bf16 MFMA GEMM, r12 fragment maps; single-buffered 2-barrier loop
// (round-1 explicit dbuf regressed: compiler drains vmcnt(0) at every
// __syncthreads anyway, and multi-block wave overlap already hides staging;
// the dbuf only added VGPR + dynamic-index VALU).
// A is now PRE-SPLIT bf16 hi|lo (xs), staged with the exact same swizzle and
// fragment map as B — the K-loop has zero split2 VALU.
// XCD swizzle (b&7 = panel group) keeps the x panel HBM-once.
// Outputs int16: q16 = q*2048 (1/8 head-scale folded), k16 = k*4096;
// consumer divides by 2^26.
// ---------------------------------------------------------------------------
__global__ __launch_bounds__(256) void gemm_mfma(
    const unsigned short* __restrict__ xs,   // [N][1024] hi|lo
    const unsigned short* __restrict__ wqs,  // [512][1024] hi|lo
    const unsigned short* __restrict__ wks,
    const float* __restrict__ q_b, const float* __restrict__ k_b,
    short* __restrict__ q16, short* __restrict__ k16) {
  __shared__ unsigned short Ah[128 * 32];  // 8 KB each
  __shared__ unsigned short Al[128 * 32];
  __shared__ unsigned short Bh[128 * 32];
  __shared__ unsigned short Bl[128 * 32];
  const int tid = threadIdx.x;
  const int w = tid >> 6;        // wave 0..3
  const int l = tid & 63;

  const int b = blockIdx.x;
  const int j = b >> 3;
  const int mb = (b & 7) * 32 + (j >> 3);
  const int c = j & 7;
  const bool is_q = ((c & 1) == 0);
  const int bm = mb * 128;
  const int bn = (c >> 1) * 128;

  const unsigned short* __restrict__ wmat = is_q ? wqs : wks;
  const float* __restrict__ bias = is_q ? q_b : k_b;
  short* __restrict__ outp = is_q ? q16 : k16;
  const float oscale = is_q ? 2048.f : 4096.f;

  const int wm = (w & 1) * 64;   // wave's m-quadrant
  const int wn = (w >> 1) * 64;  // wave's n-quadrant

  f32x4 acc[4][4];
#pragma unroll
  for (int i = 0; i < 4; ++i)
#pragma unroll
    for (int jj = 0; jj < 4; ++jj) acc[i][jj] = (f32x4){0.f, 0.f, 0.f, 0.f};

  // staging map (r7 swizzle): LDS chunk jx of row r holds global chunk
  // jx ^ ((r>>1)&3); lane l covers row w*16+(l>>2), chunk l&3.
  const int sr0 = w * 16 + (l >> 2);
  const int sr1 = sr0 + 64;
  const int sc = (((l & 3) ^ ((l >> 3) & 3)) << 3);
  // fragment map: lane wants row (base + fr), global K-chunk l>>4, which the
  // swizzle stored at chunk (l>>4) ^ ((fr>>1)&3).
  const int fr = l & 15;
  const int fcs = ((((l >> 4) ^ ((fr >> 1) & 3)) & 3) << 3);

  const unsigned short* __restrict__ wa = wmat + (size_t)bn * 1024;
  const unsigned short* __restrict__ xa = xs + (size_t)bm * 1024;

  for (int k0 = 0; k0 < 512; k0 += 32) {
    async16(xa + (size_t)sr0 * 1024 + k0 + sc, Ah + w * 512);
    async16(xa + (size_t)sr1 * 1024 + k0 + sc, Ah + (w + 4) * 512);
    async16(xa + (size_t)sr0 * 1024 + 512 + k0 + sc, Al + w * 512);
    async16(xa + (size_t)sr1 * 1024 + 512 + k0 + sc, Al + (w + 4) * 512);
    async16(wa + (size_t)sr0 * 1024 + k0 + sc, Bh + w * 512);
    async16(wa + (size_t)sr1 * 1024 + k0 + sc, Bh + (w + 4) * 512);
    async16(wa + (size_t)sr0 * 1024 + 512 + k0 + sc, Bl + w * 512);
    async16(wa + (size_t)sr1 * 1024 + 512 + k0 + sc, Bl + (w + 4) * 512);
    __syncthreads();

    bf16x8 ahi[4], alo[4], bh[4];
#pragma unroll
    for (int i = 0; i < 4; ++i)
      ahi[i] = *(const bf16x8*)(Ah + (wm + i * 16 + fr) * 32 + fcs);
#pragma unroll
    for (int i = 0; i < 4; ++i)
      alo[i] = *(const bf16x8*)(Al + (wm + i * 16 + fr) * 32 + fcs);
#pragma unroll
    for (int i = 0; i < 4; ++i)
      bh[i] = *(const bf16x8*)(Bh + (wn + i * 16 + fr) * 32 + fcs);
#pragma unroll
    for (int i = 0; i < 4; ++i)
#pragma unroll
      for (int jj = 0; jj < 4; ++jj)
        acc[i][jj] = __builtin_amdgcn_mfma_f32_16x16x32_bf16(
            ahi[i], bh[jj], acc[i][jj], 0, 0, 0);
#pragma unroll
    for (int i = 0; i < 4; ++i)
#pragma unroll
      for (int jj = 0; jj < 4; ++jj)
        acc[i][jj] = __builtin_amdgcn_mfma_f32_16x16x32_bf16(
            alo[i], bh[jj], acc[i][jj], 0, 0, 0);
#pragma unroll
    for (int jj = 0; jj < 4; ++jj)
      bh[jj] = *(const bf16x8*)(Bl + (wn + jj * 16 + fr) * 32 + fcs);
#pragma unroll
    for (int i = 0; i < 4; ++i)
#pragma unroll
      for (int jj = 0; jj < 4; ++jj)
        acc[i][jj] = __builtin_amdgcn_mfma_f32_16x16x32_bf16(
            ahi[i], bh[jj], acc[i][jj], 0, 0, 0);
    __syncthreads();
  }

  // epilogue: C/D layout col = l&15 (n), row = (l>>4)*4 + reg (m); int16 out
  const int cn = l & 15;
  const int cm4 = (l >> 4) * 4;
  float bvals[4];
#pragma unroll
  for (int jj = 0; jj < 4; ++jj) bvals[jj] = bias[bn + wn + jj * 16 + cn];
#pragma unroll
  for (int i = 0; i < 4; ++i) {
#pragma unroll
    for (int r = 0; r < 4; ++r) {
      const int m = bm + wm + i * 16 + cm4 + r;
      short* op = outp + (size_t)m * 512 + bn + wn + cn;
#pragma unroll
      for (int jj = 0; jj < 4; ++jj) {
        float v = (acc[i][jj][r] + bvals[jj]) * oscale;
        v = fmaxf(fminf(v, 32767.f), -32767.f);
        op[jj * 16] = (short)__float2int_rn(v);
      }
    }
  }
}

// ---------------------------------------------------------------------------
// Phase A: 4 edges per wave, batched loads; q AND k gathered as int16.
// logit = (sum q16*k16) / 2^26 + bias.
// ---------------------------------------------------------------------------
__global__ __launch_bounds__(256) void edge_logits(
    const short* __restrict__ q16, const short* __restrict__ k16,
    const int* __restrict__ row_index, const int* __restrict__ ge,
    const float* __restrict__ att_bias, float* __restrict__ logits) {
  const int wave = threadIdx.x >> 6;
  const int lane = threadIdx.x & 63;
  const int e0 = __builtin_amdgcn_readfirstlane((blockIdx.x * 4 + wave) * 4);

  int r[4], g[4];
#pragma unroll
  for (int i = 0; i < 4; ++i) {
    r[i] = row_index[e0 + i];
    g[i] = ge[e0 + i];
  }

  const int lo = lane * 8;
  s16x8 kv[4], qv[4];
#pragma unroll
  for (int i = 0; i < 4; ++i)
    kv[i] = *(const s16x8*)(k16 + (size_t)g[i] * E_DIM + lo);
#pragma unroll
  for (int i = 0; i < 4; ++i)
    qv[i] = *(const s16x8*)(q16 + (size_t)r[i] * E_DIM + lo);

  const int h = lane >> 3;
#pragma unroll
  for (int i = 0; i < 4; ++i) {
    float s = (float)qv[i][0] * (float)kv[i][0];
    s = fmaf((float)qv[i][1], (float)kv[i][1], s);
    s = fmaf((float)qv[i][2], (float)kv[i][2], s);
    s = fmaf((float)qv[i][3], (float)kv[i][3], s);
    s = fmaf((float)qv[i][4], (float)kv[i][4], s);
    s = fmaf((float)qv[i][5], (float)kv[i][5], s);
    s = fmaf((float)qv[i][6], (float)kv[i][6], s);
    s = fmaf((float)qv[i][7], (float)kv[i][7], s);
    s += __shfl_xor(s, 1);
    s += __shfl_xor(s, 2);
    s += __shfl_xor(s, 4);
    if ((lane & 7) == 0) {
      logits[(size_t)(e0 + i) * H_HEADS + h] =
          s * (1.f / 67108864.f) + att_bias[(size_t)h * NNZ_E + e0 + i];
    }
  }
}

// ---------------------------------------------------------------------------
// Phase B: 4 rows per block (1 wave per row); lane (h,j) strided
// online-softmax + 3-step merge.
// ---------------------------------------------------------------------------
__global__ __launch_bounds__(256) void row_featurize(
    const float* __restrict__ logits, const int* __restrict__ row_start,
    const int* __restrict__ col_index, const float* __restrict__ dist,
    const float* __restrict__ pos, const float* __restrict__ col_pos,
    float* __restrict__ out) {
  const int r = blockIdx.x * 4 + (threadIdx.x >> 6);
  const int lane = threadIdx.x & 63;
  const int h = lane >> 3;
  const int j = lane & 7;
  const int start = row_start[r];
  const int end = row_start[r + 1];

  float m = -INFINITY, l = 0.f, accw = 0.f, a0 = 0.f, a1 = 0.f, a2 = 0.f;

  for (int e = start + j; e < end; e += 8) {
    const float s = logits[(size_t)e * H_HEADS + h];
    const float dd = dist[e];
    const float w = (dd == 0.f) ? 0.f : 1.f / dd;
    const int c = col_index[e];
    const float nm = fmaxf(m, s);
    const float sc = __expf(m - nm);
    const float p = __expf(s - nm);
    m = nm;
    l = fmaf(l, sc, p);
    const float pw = p * w;
    accw = fmaf(accw, sc, pw);
    a0 = fmaf(a0, sc, pw * col_pos[c * 3 + 0]);
    a1 = fmaf(a1, sc, pw * col_pos[c * 3 + 1]);
    a2 = fmaf(a2, sc, pw * col_pos[c * 3 + 2]);
  }

#pragma unroll
  for (int off = 1; off < 8; off <<= 1) {
    const float mo = __shfl_xor(m, off);
    const float lo = __shfl_xor(l, off);
    const float wo = __shfl_xor(accw, off);
    const float b0 = __shfl_xor(a0, off);
    const float b1 = __shfl_xor(a1, off);
    const float b2 = __shfl_xor(a2, off);
    const float nm = fmaxf(m, mo);
    const float s1 = __expf(fmaxf(m - nm, -80.f));  // NaN (inf-inf) -> -80
    const float s2 = __expf(fmaxf(mo - nm, -80.f));
    m = nm;
    l = l * s1 + lo * s2;
    accw = accw * s1 + wo * s2;
    a0 = a0 * s1 + b0 * s2;
    a1 = a1 * s1 + b1 * s2;
    a2 = a2 * s1 + b2 * s2;
  }

  if (j == 0) {
    const float invz = (l > 0.f) ? 1.f / l : 0.f;
    const float avg = accw * invz;
    const float v0 = a0 * invz - avg * pos[r * 3 + 0];
    const float v1 = a1 * invz - avg * pos[r * 3 + 1];
    const float v2 = a2 * invz - avg * pos[r * 3 + 2];
    const float nrm = sqrtf(v0 * v0 + v1 * v1 + v2 * v2);
    const float invn = 1.f / fmaxf(nrm, 1e-12f);
    float4 o;
    o.x = v0 * invn; o.y = v1 * invn; o.z = v2 * invn; o.w = avg;
    *(float4*)(out + (size_t)r * (H_HEADS * 4) + h * 4) = o;
  }
}

// ---------------------------------------------------------------------------
extern "C" void kernel_launch(void* const* d_in, const int* in_sizes, int n_in,
                              void* d_out, int out_size, void* d_ws,
                              size_t ws_size, hipStream_t stream) {
  const float* x        = (const float*)d_in[0];
  const int* row_index  = (const int*)d_in[1];
  const int* col_index  = (const int*)d_in[2];
  const int* to_col     = (const int*)d_in[3];
  const float* att_bias = (const float*)d_in[4];
  const float* dist     = (const float*)d_in[5];
  const float* pos      = (const float*)d_in[6];
  const float* col_pos  = (const float*)d_in[7];
  const float* q_w      = (const float*)d_in[8];
  const float* q_b      = (const float*)d_in[9];
  const float* k_w      = (const float*)d_in[10];
  const float* k_b      = (const float*)d_in[11];
  float* out = (float*)d_out;

  // ws: q16[N*E s16] | k16[N*E s16] | xs[N*1024 u16] | wq_s | wk_s
  //     | row_start[N+1] | ge[NNZ]
  // logits[NNZ*H f32] ALIASES xs: xs lifetime = prep+gemm, logits lifetime =
  // edge_logits+row_featurize — disjoint. Keeps ws at ~132 MB.
  short* q16 = (short*)d_ws;
  short* k16 = q16 + (size_t)N_NODES * E_DIM;
  unsigned short* xs = (unsigned short*)(k16 + (size_t)N_NODES * E_DIM);
  float* logits = (float*)xs;
  unsigned short* wq_s = xs + (size_t)N_NODES * 1024;
  unsigned short* wk_s = wq_s + 512 * 1024;
  int* row_start = (int*)(wk_s + 512 * 1024);
  int* ge = row_start + (N_NODES + 1);

  prep_small<<<512 + 16384 + NNZ_E / 256, 256, 0, stream>>>(
      x, q_w, k_w, row_index, col_index, to_col, wq_s, wk_s, xs, row_start, ge);

  gemm_mfma<<<2048, 256, 0, stream>>>(xs, wq_s, wk_s, q_b, k_b, q16, k16);

  edge_logits<<<NNZ_E / 16, 256, 0, stream>>>(q16, k16, row_index, ge,
                                              att_bias, logits);
  row_featurize<<<N_NODES / 4, 256, 0, stream>>>(logits, row_start, col_index,
                                                 dist, pos, col_pos, out);
}

// Round 3
// 334.451 us; speedup vs baseline: 1.0438x; 1.0207x over previous
//
#include <hip/hip_runtime.h>
#include <math.h>
#include <stdint.h>

#define N_NODES 32768
#define E_DIM   512
#define H_HEADS 8
#define D_HEAD  64
#define NNZ_E   524288

typedef __attribute__((ext_vector_type(4))) float f32x4;
typedef __attribute__((ext_vector_type(8))) short bf16x8;  // 8 bf16 = 4 VGPRs
typedef __attribute__((ext_vector_type(8))) short s16x8;

__device__ __forceinline__ unsigned short f32_to_bf16_rne(float f) {
  union { float f; uint32_t u; } v; v.f = f;
  const uint32_t u = v.u;
  return (unsigned short)((u + 0x7FFFu + ((u >> 16) & 1u)) >> 16);
}
__device__ __forceinline__ float bf16_to_f32(unsigned short h) {
  union { uint32_t u; float f; } v; v.u = ((uint32_t)h) << 16;
  return v.f;
}

// async 16B global->LDS (wave-uniform LDS base + lane*16)
__device__ __forceinline__ void async16(const void* g, void* l) {
  __builtin_amdgcn_global_load_lds(
      (const __attribute__((address_space(1))) void*)g,
      (__attribute__((address_space(3))) void*)l, 16, 0, 0);
}

// ---------------------------------------------------------------------------
// prep_small:
//   blocks [0,256)            : split q_w  -> wq_s (bf16 hi|lo, [512][1024])
//   blocks [256,512)          : split k_w  -> wk_s
//   blocks [512,512+16384)    : split x    -> xs   (bf16 hi|lo, [32768][1024])
//   blocks [512+16384, ...)   : ge + CSR row_start
// ---------------------------------------------------------------------------
__global__ __launch_bounds__(256) void prep_small(
    const float* __restrict__ x,
    const float* __restrict__ q_w, const float* __restrict__ k_w,
    const int* __restrict__ row_index, const int* __restrict__ col_index,
    const int* __restrict__ to_col,
    unsigned short* __restrict__ wq_s, unsigned short* __restrict__ wk_s,
    unsigned short* __restrict__ xs,
    int* __restrict__ row_start, int* __restrict__ ge) {
  const int b = blockIdx.x;
  if (b < 512 + 16384) {
    const float* src;
    unsigned short* dst;
    int t;
    if (b < 256)      { src = q_w; dst = wq_s; t = b * 256 + threadIdx.x; }
    else if (b < 512) { src = k_w; dst = wk_s; t = (b - 256) * 256 + threadIdx.x; }
    else              { src = x;   dst = xs;   t = (b - 512) * 256 + threadIdx.x; }
    const int r = t >> 7;
    const int c4 = (t & 127) << 2;
    const float4 v = *(const float4*)(src + (size_t)r * 512 + c4);
    ushort4 hi, lo;
    hi.x = f32_to_bf16_rne(v.x); lo.x = f32_to_bf16_rne(v.x - bf16_to_f32(hi.x));
    hi.y = f32_to_bf16_rne(v.y); lo.y = f32_to_bf16_rne(v.y - bf16_to_f32(hi.y));
    hi.z = f32_to_bf16_rne(v.z); lo.z = f32_to_bf16_rne(v.z - bf16_to_f32(hi.z));
    hi.w = f32_to_bf16_rne(v.w); lo.w = f32_to_bf16_rne(v.w - bf16_to_f32(hi.w));
    *(ushort4*)(dst + (size_t)r * 1024 + c4) = hi;
    *(ushort4*)(dst + (size_t)r * 1024 + 512 + c4) = lo;
  } else {
    const int e = (b - 512 - 16384) * 256 + threadIdx.x;
    if (e < NNZ_E) {
      ge[e] = to_col[col_index[e]];
      const int r0 = row_index[e];
      const int r1 = (e + 1 < NNZ_E) ? row_index[e + 1] : N_NODES;
      if (e == 0)
        for (int r = 0; r <= r0; ++r) row_start[r] = 0;
      for (int r = r0 + 1; r <= r1; ++r) row_start[r] = e + 1;
    }
  }
}

// ---------------------------------------------------------------------------
// Split-bf16 MFMA GEMM. Round-2 sat at the m97-structure plateau (MfmaUtil
// 37%): stage latency fully exposed between stage and __syncthreads drain.
// Now: T3-minimum counted-vmcnt pipeline (T4) + setprio (T5).
//   STAGE(nxt) ; s_waitcnt vmcnt(8)  <- waits ONLY the older 8 loads (cur);
//   s_barrier  ; ds_read(cur) ; lgkmcnt(0)+sched_barrier ; s_barrier ;
//   setprio(1) 48xMFMA setprio(0)
// Loads for tile k+1 stay in flight ACROSS both barriers (the round-1
// failure was __syncthreads' implicit vmcnt(0) drain killing exactly this).
// Hazards: RAW buf[cur] = vmcnt(8)+bar1 (all waves waited their own 8, then
// joined). WAR on stage target = previous iteration's bar2 (every wave's
// ds_reads explicitly lgkm-drained before it). Uniform control flow.
// Numerics: identical MFMA order to round-2 (bit-identical output).
// ---------------------------------------------------------------------------
__global__ __launch_bounds__(256) void gemm_mfma(
    const unsigned short* __restrict__ xs,   // [N][1024] hi|lo
    const unsigned short* __restrict__ wqs,  // [512][1024] hi|lo
    const unsigned short* __restrict__ wks,
    const float* __restrict__ q_b, const float* __restrict__ k_b,
    short* __restrict__ q16, short* __restrict__ k16) {
  __shared__ unsigned short Ah[2 * 4096];  // 2 x 8 KB each (64 KB total)
  __shared__ unsigned short Al[2 * 4096];
  __shared__ unsigned short Bh[2 * 4096];
  __shared__ unsigned short Bl[2 * 4096];
  const int tid = threadIdx.x;
  const int w = tid >> 6;        // wave 0..3
  const int l = tid & 63;

  const int b = blockIdx.x;
  const int j = b >> 3;
  const int mb = (b & 7) * 32 + (j >> 3);
  const int c = j & 7;
  const bool is_q = ((c & 1) == 0);
  const int bm = mb * 128;
  const int bn = (c >> 1) * 128;

  const unsigned short* __restrict__ wmat = is_q ? wqs : wks;
  const float* __restrict__ bias = is_q ? q_b : k_b;
  short* __restrict__ outp = is_q ? q16 : k16;
  const float oscale = is_q ? 2048.f : 4096.f;

  const int wm = (w & 1) * 64;   // wave's m-quadrant
  const int wn = (w >> 1) * 64;  // wave's n-quadrant

  f32x4 acc[4][4];
#pragma unroll
  for (int i = 0; i < 4; ++i)
#pragma unroll
    for (int jj = 0; jj < 4; ++jj) acc[i][jj] = (f32x4){0.f, 0.f, 0.f, 0.f};

  // staging map (r7 swizzle): LDS chunk jx of row r holds global chunk
  // jx ^ ((r>>1)&3); lane l covers row w*16+(l>>2), chunk l&3.
  const int sr0 = w * 16 + (l >> 2);
  const int sr1 = sr0 + 64;
  const int sc = (((l & 3) ^ ((l >> 3) & 3)) << 3);
  // fragment map: lane wants row (base + fr), global K-chunk l>>4, stored at
  // chunk (l>>4) ^ ((fr>>1)&3).
  const int fr = l & 15;
  const int fcs = ((((l >> 4) ^ ((fr >> 1) & 3)) & 3) << 3);

  const unsigned short* __restrict__ wa = wmat + (size_t)bn * 1024;
  const unsigned short* __restrict__ xa = xs + (size_t)bm * 1024;

#define STAGE(k0, bf)                                                       \
  do {                                                                      \
    async16(xa + (size_t)sr0 * 1024 + (k0) + sc, Ah + (bf)*4096 + w * 512); \
    async16(xa + (size_t)sr1 * 1024 + (k0) + sc,                            \
            Ah + (bf)*4096 + (w + 4) * 512);                                \
    async16(xa + (size_t)sr0 * 1024 + 512 + (k0) + sc,                      \
            Al + (bf)*4096 + w * 512);                                      \
    async16(xa + (size_t)sr1 * 1024 + 512 + (k0) + sc,                      \
            Al + (bf)*4096 + (w + 4) * 512);                                \
    async16(wa + (size_t)sr0 * 1024 + (k0) + sc, Bh + (bf)*4096 + w * 512); \
    async16(wa + (size_t)sr1 * 1024 + (k0) + sc,                            \
            Bh + (bf)*4096 + (w + 4) * 512);                                \
    async16(wa + (size_t)sr0 * 1024 + 512 + (k0) + sc,                      \
            Bl + (bf)*4096 + w * 512);                                      \
    async16(wa + (size_t)sr1 * 1024 + 512 + (k0) + sc,                      \
            Bl + (bf)*4096 + (w + 4) * 512);                                \
  } while (0)

  // prologue: stage K-step 0 into buffer 0, drain, join.
  STAGE(0, 0);
  asm volatile("s_waitcnt vmcnt(0)" ::: "memory");
  asm volatile("s_barrier" ::: "memory");

#pragma unroll
  for (int ks = 0; ks < 16; ++ks) {
    const int cur = ks & 1;
    if (ks < 15) {
      STAGE((ks + 1) * 32, cur ^ 1);
      // wait my 8 OLDER loads (tile cur, issued last iter); the 8 just
      // issued stay in flight across both barriers.
      asm volatile("s_waitcnt vmcnt(8)" ::: "memory");
    } else {
      asm volatile("s_waitcnt vmcnt(0)" ::: "memory");
    }
    asm volatile("s_barrier" ::: "memory");  // all waves' cur tile in LDS

    const unsigned short* Ahc = Ah + cur * 4096;
    const unsigned short* Alc = Al + cur * 4096;
    const unsigned short* Bhc = Bh + cur * 4096;
    const unsigned short* Blc = Bl + cur * 4096;

    bf16x8 ahi[4], alo[4], bhv[4], blv[4];
#pragma unroll
    for (int i = 0; i < 4; ++i)
      ahi[i] = *(const bf16x8*)(Ahc + (wm + i * 16 + fr) * 32 + fcs);
#pragma unroll
    for (int i = 0; i < 4; ++i)
      alo[i] = *(const bf16x8*)(Alc + (wm + i * 16 + fr) * 32 + fcs);
#pragma unroll
    for (int i = 0; i < 4; ++i)
      bhv[i] = *(const bf16x8*)(Bhc + (wn + i * 16 + fr) * 32 + fcs);
#pragma unroll
    for (int i = 0; i < 4; ++i)
      blv[i] = *(const bf16x8*)(Blc + (wn + i * 16 + fr) * 32 + fcs);

    // my ds_reads must be DONE before signalling bar2 (next iter's stage
    // overwrites this buffer).
    asm volatile("s_waitcnt lgkmcnt(0)" ::: "memory");
    __builtin_amdgcn_sched_barrier(0);
    asm volatile("s_barrier" ::: "memory");

    __builtin_amdgcn_s_setprio(1);
#pragma unroll
    for (int i = 0; i < 4; ++i)
#pragma unroll
      for (int jj = 0; jj < 4; ++jj)
        acc[i][jj] = __builtin_amdgcn_mfma_f32_16x16x32_bf16(
            ahi[i], bhv[jj], acc[i][jj], 0, 0, 0);
#pragma unroll
    for (int i = 0; i < 4; ++i)
#pragma unroll
      for (int jj = 0; jj < 4; ++jj)
        acc[i][jj] = __builtin_amdgcn_mfma_f32_16x16x32_bf16(
            alo[i], bhv[jj], acc[i][jj], 0, 0, 0);
#pragma unroll
    for (int i = 0; i < 4; ++i)
#pragma unroll
      for (int jj = 0; jj < 4; ++jj)
        acc[i][jj] = __builtin_amdgcn_mfma_f32_16x16x32_bf16(
            ahi[i], blv[jj], acc[i][jj], 0, 0, 0);
    __builtin_amdgcn_s_setprio(0);
  }
#undef STAGE

  // epilogue: C/D layout col = l&15 (n), row = (l>>4)*4 + reg (m); int16 out
  const int cn = l & 15;
  const int cm4 = (l >> 4) * 4;
  float bvals[4];
#pragma unroll
  for (int jj = 0; jj < 4; ++jj) bvals[jj] = bias[bn + wn + jj * 16 + cn];
#pragma unroll
  for (int i = 0; i < 4; ++i) {
#pragma unroll
    for (int r = 0; r < 4; ++r) {
      const int m = bm + wm + i * 16 + cm4 + r;
      short* op = outp + (size_t)m * 512 + bn + wn + cn;
#pragma unroll
      for (int jj = 0; jj < 4; ++jj) {
        float v = (acc[i][jj][r] + bvals[jj]) * oscale;
        v = fmaxf(fminf(v, 32767.f), -32767.f);
        op[jj * 16] = (short)__float2int_rn(v);
      }
    }
  }
}

// ---------------------------------------------------------------------------
// Phase A: 8 edges per wave (was 4) — the k16 gather is random 1KB rows from
// L2/L3 (512 MB logical), latency-bound; doubling edges-in-flight doubles
// MLP (16 outstanding 16B loads/lane) for ~32 extra VGPR.
// logit = (sum q16*k16) / 2^26 + bias.
// ---------------------------------------------------------------------------
__global__ __launch_bounds__(256) void edge_logits(
    const short* __restrict__ q16, const short* __restrict__ k16,
    const int* __restrict__ row_index, const int* __restrict__ ge,
    const float* __restrict__ att_bias, float* __restrict__ logits) {
  const int wave = threadIdx.x >> 6;
  const int lane = threadIdx.x & 63;
  const int e0 = __builtin_amdgcn_readfirstlane((blockIdx.x * 4 + wave) * 8);

  int r[8], g[8];
#pragma unroll
  for (int i = 0; i < 8; ++i) {
    r[i] = row_index[e0 + i];
    g[i] = ge[e0 + i];
  }

  const int lo = lane * 8;
  s16x8 kv[8], qv[8];
#pragma unroll
  for (int i = 0; i < 8; ++i)
    kv[i] = *(const s16x8*)(k16 + (size_t)g[i] * E_DIM + lo);
#pragma unroll
  for (int i = 0; i < 8; ++i)
    qv[i] = *(const s16x8*)(q16 + (size_t)r[i] * E_DIM + lo);

  const int h = lane >> 3;
#pragma unroll
  for (int i = 0; i < 8; ++i) {
    float s = (float)qv[i][0] * (float)kv[i][0];
    s = fmaf((float)qv[i][1], (float)kv[i][1], s);
    s = fmaf((float)qv[i][2], (float)kv[i][2], s);
    s = fmaf((float)qv[i][3], (float)kv[i][3], s);
    s = fmaf((float)qv[i][4], (float)kv[i][4], s);
    s = fmaf((float)qv[i][5], (float)kv[i][5], s);
    s = fmaf((float)qv[i][6], (float)kv[i][6], s);
    s = fmaf((float)qv[i][7], (float)kv[i][7], s);
    s += __shfl_xor(s, 1);
    s += __shfl_xor(s, 2);
    s += __shfl_xor(s, 4);
    if ((lane & 7) == 0) {
      logits[(size_t)(e0 + i) * H_HEADS + h] =
          s * (1.f / 67108864.f) + att_bias[(size_t)h * NNZ_E + e0 + i];
    }
  }
}

// ---------------------------------------------------------------------------
// Phase B: 4 rows per block (1 wave per row); lane (h,j) strided
// online-softmax + 3-step merge.
// ---------------------------------------------------------------------------
__global__ __launch_bounds__(256) void row_featurize(
    const float* __restrict__ logits, const int* __restrict__ row_start,
    const int* __restrict__ col_index, const float* __restrict__ dist,
    const float* __restrict__ pos, const float* __restrict__ col_pos,
    float* __restrict__ out) {
  const int r = blockIdx.x * 4 + (threadIdx.x >> 6);
  const int lane = threadIdx.x & 63;
  const int h = lane >> 3;
  const int j = lane & 7;
  const int start = row_start[r];
  const int end = row_start[r + 1];

  float m = -INFINITY, l = 0.f, accw = 0.f, a0 = 0.f, a1 = 0.f, a2 = 0.f;

  for (int e = start + j; e < end; e += 8) {
    const float s = logits[(size_t)e * H_HEADS + h];
    const float dd = dist[e];
    const float w = (dd == 0.f) ? 0.f : 1.f / dd;
    const int c = col_index[e];
    const float nm = fmaxf(m, s);
    const float sc = __expf(m - nm);
    const float p = __expf(s - nm);
    m = nm;
    l = fmaf(l, sc, p);
    const float pw = p * w;
    accw = fmaf(accw, sc, pw);
    a0 = fmaf(a0, sc, pw * col_pos[c * 3 + 0]);
    a1 = fmaf(a1, sc, pw * col_pos[c * 3 + 1]);
    a2 = fmaf(a2, sc, pw * col_pos[c * 3 + 2]);
  }

#pragma unroll
  for (int off = 1; off < 8; off <<= 1) {
    const float mo = __shfl_xor(m, off);
    const float lo = __shfl_xor(l, off);
    const float wo = __shfl_xor(accw, off);
    const float b0 = __shfl_xor(a0, off);
    const float b1 = __shfl_xor(a1, off);
    const float b2 = __shfl_xor(a2, off);
    const float nm = fmaxf(m, mo);
    const float s1 = __expf(fmaxf(m - nm, -80.f));  // NaN (inf-inf) -> -80
    const float s2 = __expf(fmaxf(mo - nm, -80.f));
    m = nm;
    l = l * s1 + lo * s2;
    accw = accw * s1 + wo * s2;
    a0 = a0 * s1 + b0 * s2;
    a1 = a1 * s1 + b1 * s2;
    a2 = a2 * s1 + b2 * s2;
  }

  if (j == 0) {
    const float invz = (l > 0.f) ? 1.f / l : 0.f;
    const float avg = accw * invz;
    const float v0 = a0 * invz - avg * pos[r * 3 + 0];
    const float v1 = a1 * invz - avg * pos[r * 3 + 1];
    const float v2 = a2 * invz - avg * pos[r * 3 + 2];
    const float nrm = sqrtf(v0 * v0 + v1 * v1 + v2 * v2);
    const float invn = 1.f / fmaxf(nrm, 1e-12f);
    float4 o;
    o.x = v0 * invn; o.y = v1 * invn; o.z = v2 * invn; o.w = avg;
    *(float4*)(out + (size_t)r * (H_HEADS * 4) + h * 4) = o;
  }
}

// ---------------------------------------------------------------------------
extern "C" void kernel_launch(void* const* d_in, const int* in_sizes, int n_in,
                              void* d_out, int out_size, void* d_ws,
                              size_t ws_size, hipStream_t stream) {
  const float* x        = (const float*)d_in[0];
  const int* row_index  = (const int*)d_in[1];
  const int* col_index  = (const int*)d_in[2];
  const int* to_col     = (const int*)d_in[3];
  const float* att_bias = (const float*)d_in[4];
  const float* dist     = (const float*)d_in[5];
  const float* pos      = (const float*)d_in[6];
  const float* col_pos  = (const float*)d_in[7];
  const float* q_w      = (const float*)d_in[8];
  const float* q_b      = (const float*)d_in[9];
  const float* k_w      = (const float*)d_in[10];
  const float* k_b      = (const float*)d_in[11];
  float* out = (float*)d_out;

  // ws: q16[N*E s16] | k16[N*E s16] | xs[N*1024 u16] | wq_s | wk_s
  //     | row_start[N+1] | ge[NNZ]
  // logits[NNZ*H f32] ALIASES xs (disjoint lifetimes).
  short* q16 = (short*)d_ws;
  short* k16 = q16 + (size_t)N_NODES * E_DIM;
  unsigned short* xs = (unsigned short*)(k16 + (size_t)N_NODES * E_DIM);
  float* logits = (float*)xs;
  unsigned short* wq_s = xs + (size_t)N_NODES * 1024;
  unsigned short* wk_s = wq_s + 512 * 1024;
  int* row_start = (int*)(wk_s + 512 * 1024);
  int* ge = row_start + (N_NODES + 1);

  prep_small<<<512 + 16384 + NNZ_E / 256, 256, 0, stream>>>(
      x, q_w, k_w, row_index, col_index, to_col, wq_s, wk_s, xs, row_start, ge);

  gemm_mfma<<<2048, 256, 0, stream>>>(xs, wq_s, wk_s, q_b, k_b, q16, k16);

  edge_logits<<<NNZ_E / 32, 256, 0, stream>>>(q16, k16, row_index, ge,
                                              att_bias, logits);
  row_featurize<<<N_NODES / 4, 256, 0, stream>>>(logits, row_start, col_index,
                                                 dist, pos, col_pos, out);
}

// Round 4
// 320.379 us; speedup vs baseline: 1.0896x; 1.0439x over previous
//
#include <hip/hip_runtime.h>
#include <math.h>
#include <stdint.h>

#define N_NODES 32768
#define E_DIM   512
#define H_HEADS 8
#define D_HEAD  64
#define NNZ_E   524288

typedef __attribute__((ext_vector_type(4))) float f32x4;
typedef __attribute__((ext_vector_type(8))) short bf16x8;  // 8 bf16 = 4 VGPRs
typedef __attribute__((ext_vector_type(8))) short s16x8;

__device__ __forceinline__ unsigned short f32_to_bf16_rne(float f) {
  union { float f; uint32_t u; } v; v.f = f;
  const uint32_t u = v.u;
  return (unsigned short)((u + 0x7FFFu + ((u >> 16) & 1u)) >> 16);
}
__device__ __forceinline__ float bf16_to_f32(unsigned short h) {
  union { uint32_t u; float f; } v; v.u = ((uint32_t)h) << 16;
  return v.f;
}

// async 16B global->LDS (wave-uniform LDS base + lane*16)
__device__ __forceinline__ void async16(const void* g, void* l) {
  __builtin_amdgcn_global_load_lds(
      (const __attribute__((address_space(1))) void*)g,
      (__attribute__((address_space(3))) void*)l, 16, 0, 0);
}

// ---------------------------------------------------------------------------
// prep_small:
//   blocks [0,256)            : split q_w  -> wq_s (bf16 hi|lo, [512][1024])
//   blocks [256,512)          : split k_w  -> wk_s
//   blocks [512,512+16384)    : split x    -> xs   (bf16 hi|lo, [32768][1024])
//   blocks [512+16384, ...)   : ge + CSR row_start
// ---------------------------------------------------------------------------
__global__ __launch_bounds__(256) void prep_small(
    const float* __restrict__ x,
    const float* __restrict__ q_w, const float* __restrict__ k_w,
    const int* __restrict__ row_index, const int* __restrict__ col_index,
    const int* __restrict__ to_col,
    unsigned short* __restrict__ wq_s, unsigned short* __restrict__ wk_s,
    unsigned short* __restrict__ xs,
    int* __restrict__ row_start, int* __restrict__ ge) {
  const int b = blockIdx.x;
  if (b < 512 + 16384) {
    const float* src;
    unsigned short* dst;
    int t;
    if (b < 256)      { src = q_w; dst = wq_s; t = b * 256 + threadIdx.x; }
    else if (b < 512) { src = k_w; dst = wk_s; t = (b - 256) * 256 + threadIdx.x; }
    else              { src = x;   dst = xs;   t = (b - 512) * 256 + threadIdx.x; }
    const int r = t >> 7;
    const int c4 = (t & 127) << 2;
    const float4 v = *(const float4*)(src + (size_t)r * 512 + c4);
    ushort4 hi, lo;
    hi.x = f32_to_bf16_rne(v.x); lo.x = f32_to_bf16_rne(v.x - bf16_to_f32(hi.x));
    hi.y = f32_to_bf16_rne(v.y); lo.y = f32_to_bf16_rne(v.y - bf16_to_f32(hi.y));
    hi.z = f32_to_bf16_rne(v.z); lo.z = f32_to_bf16_rne(v.z - bf16_to_f32(hi.z));
    hi.w = f32_to_bf16_rne(v.w); lo.w = f32_to_bf16_rne(v.w - bf16_to_f32(hi.w));
    *(ushort4*)(dst + (size_t)r * 1024 + c4) = hi;
    *(ushort4*)(dst + (size_t)r * 1024 + 512 + c4) = lo;
  } else {
    const int e = (b - 512 - 16384) * 256 + threadIdx.x;
    if (e < NNZ_E) {
      ge[e] = to_col[col_index[e]];
      const int r0 = row_index[e];
      const int r1 = (e + 1 < NNZ_E) ? row_index[e + 1] : N_NODES;
      if (e == 0)
        for (int r = 0; r <= r0; ++r) row_start[r] = 0;
      for (int r = r0 + 1; r <= r1; ++r) row_start[r] = e + 1;
    }
  }
}

// ---------------------------------------------------------------------------
// Split-bf16 MFMA GEMM — round-2 structure (known-good 121 us, MfmaUtil 37%,
// 0 bank conflicts). Round-3's counted-vmcnt 2-deep pipeline was null (127):
// T4 requires the 8-phase fine interleave to pay (regime gate, m230/m248).
// A is PRE-SPLIT bf16 hi|lo (xs), staged with the same swizzle/fragment map
// as B — zero conversion VALU in the K-loop.
// Outputs int16: q16 = q*2048 (1/8 head-scale folded), k16 = k*4096;
// consumer divides by 2^26.
// ---------------------------------------------------------------------------
__global__ __launch_bounds__(256) void gemm_mfma(
    const unsigned short* __restrict__ xs,   // [N][1024] hi|lo
    const unsigned short* __restrict__ wqs,  // [512][1024] hi|lo
    const unsigned short* __restrict__ wks,
    const float* __restrict__ q_b, const float* __restrict__ k_b,
    short* __restrict__ q16, short* __restrict__ k16) {
  __shared__ unsigned short Ah[128 * 32];  // 8 KB each
  __shared__ unsigned short Al[128 * 32];
  __shared__ unsigned short Bh[128 * 32];
  __shared__ unsigned short Bl[128 * 32];
  const int tid = threadIdx.x;
  const int w = tid >> 6;        // wave 0..3
  const int l = tid & 63;

  const int b = blockIdx.x;
  const int j = b >> 3;
  const int mb = (b & 7) * 32 + (j >> 3);
  const int c = j & 7;
  const bool is_q = ((c & 1) == 0);
  const int bm = mb * 128;
  const int bn = (c >> 1) * 128;

  const unsigned short* __restrict__ wmat = is_q ? wqs : wks;
  const float* __restrict__ bias = is_q ? q_b : k_b;
  short* __restrict__ outp = is_q ? q16 : k16;
  const float oscale = is_q ? 2048.f : 4096.f;

  const int wm = (w & 1) * 64;   // wave's m-quadrant
  const int wn = (w >> 1) * 64;  // wave's n-quadrant

  f32x4 acc[4][4];
#pragma unroll
  for (int i = 0; i < 4; ++i)
#pragma unroll
    for (int jj = 0; jj < 4; ++jj) acc[i][jj] = (f32x4){0.f, 0.f, 0.f, 0.f};

  // staging map (r7 swizzle): LDS chunk jx of row r holds global chunk
  // jx ^ ((r>>1)&3); lane l covers row w*16+(l>>2), chunk l&3.
  const int sr0 = w * 16 + (l >> 2);
  const int sr1 = sr0 + 64;
  const int sc = (((l & 3) ^ ((l >> 3) & 3)) << 3);
  // fragment map: lane wants row (base + fr), global K-chunk l>>4, stored at
  // chunk (l>>4) ^ ((fr>>1)&3).
  const int fr = l & 15;
  const int fcs = ((((l >> 4) ^ ((fr >> 1) & 3)) & 3) << 3);

  const unsigned short* __restrict__ wa = wmat + (size_t)bn * 1024;
  const unsigned short* __restrict__ xa = xs + (size_t)bm * 1024;

  for (int k0 = 0; k0 < 512; k0 += 32) {
    async16(xa + (size_t)sr0 * 1024 + k0 + sc, Ah + w * 512);
    async16(xa + (size_t)sr1 * 1024 + k0 + sc, Ah + (w + 4) * 512);
    async16(xa + (size_t)sr0 * 1024 + 512 + k0 + sc, Al + w * 512);
    async16(xa + (size_t)sr1 * 1024 + 512 + k0 + sc, Al + (w + 4) * 512);
    async16(wa + (size_t)sr0 * 1024 + k0 + sc, Bh + w * 512);
    async16(wa + (size_t)sr1 * 1024 + k0 + sc, Bh + (w + 4) * 512);
    async16(wa + (size_t)sr0 * 1024 + 512 + k0 + sc, Bl + w * 512);
    async16(wa + (size_t)sr1 * 1024 + 512 + k0 + sc, Bl + (w + 4) * 512);
    __syncthreads();

    bf16x8 ahi[4], alo[4], bh[4];
#pragma unroll
    for (int i = 0; i < 4; ++i)
      ahi[i] = *(const bf16x8*)(Ah + (wm + i * 16 + fr) * 32 + fcs);
#pragma unroll
    for (int i = 0; i < 4; ++i)
      alo[i] = *(const bf16x8*)(Al + (wm + i * 16 + fr) * 32 + fcs);
#pragma unroll
    for (int i = 0; i < 4; ++i)
      bh[i] = *(const bf16x8*)(Bh + (wn + i * 16 + fr) * 32 + fcs);
#pragma unroll
    for (int i = 0; i < 4; ++i)
#pragma unroll
      for (int jj = 0; jj < 4; ++jj)
        acc[i][jj] = __builtin_amdgcn_mfma_f32_16x16x32_bf16(
            ahi[i], bh[jj], acc[i][jj], 0, 0, 0);
#pragma unroll
    for (int i = 0; i < 4; ++i)
#pragma unroll
      for (int jj = 0; jj < 4; ++jj)
        acc[i][jj] = __builtin_amdgcn_mfma_f32_16x16x32_bf16(
            alo[i], bh[jj], acc[i][jj], 0, 0, 0);
#pragma unroll
    for (int jj = 0; jj < 4; ++jj)
      bh[jj] = *(const bf16x8*)(Bl + (wn + jj * 16 + fr) * 32 + fcs);
#pragma unroll
    for (int i = 0; i < 4; ++i)
#pragma unroll
      for (int jj = 0; jj < 4; ++jj)
        acc[i][jj] = __builtin_amdgcn_mfma_f32_16x16x32_bf16(
            ahi[i], bh[jj], acc[i][jj], 0, 0, 0);
    __syncthreads();
  }

  // epilogue: C/D layout col = l&15 (n), row = (l>>4)*4 + reg (m); int16 out
  const int cn = l & 15;
  const int cm4 = (l >> 4) * 4;
  float bvals[4];
#pragma unroll
  for (int jj = 0; jj < 4; ++jj) bvals[jj] = bias[bn + wn + jj * 16 + cn];
#pragma unroll
  for (int i = 0; i < 4; ++i) {
#pragma unroll
    for (int r = 0; r < 4; ++r) {
      const int m = bm + wm + i * 16 + cm4 + r;
      short* op = outp + (size_t)m * 512 + bn + wn + cn;
#pragma unroll
      for (int jj = 0; jj < 4; ++jj) {
        float v = (acc[i][jj][r] + bvals[jj]) * oscale;
        v = fmaxf(fminf(v, 32767.f), -32767.f);
        op[jj * 16] = (short)__float2int_rn(v);
      }
    }
  }
}

// ---------------------------------------------------------------------------
// row_fused: edge_logits + row_featurize in ONE kernel, CSR row-owned.
// One wave per row. q row loaded ONCE into registers (lane l: q16[r][8l..8l+8],
// head h=l>>3); edges processed serially with 2-edge unroll for MLP. Per
// edge: gather k row (16B/lane), 8-lane butterfly dot -> every lane of the
// head group holds the full head logit; online-softmax update runs
// identically in all 8 lanes (no cross-lane merge needed at the end).
// Logits never touch memory (kills the 16MB write + 16MB read round-trip);
// q traffic drops ~8x (was re-gathered per edge, row_index sorted).
// ---------------------------------------------------------------------------
__global__ __launch_bounds__(256) void row_fused(
    const short* __restrict__ q16, const short* __restrict__ k16,
    const int* __restrict__ row_start, const int* __restrict__ ge,
    const float* __restrict__ att_bias, const int* __restrict__ col_index,
    const float* __restrict__ dist, const float* __restrict__ pos,
    const float* __restrict__ col_pos, float* __restrict__ out) {
  const int r = blockIdx.x * 4 + (threadIdx.x >> 6);
  const int lane = threadIdx.x & 63;
  const int h = lane >> 3;
  const int start = row_start[r];
  const int end = row_start[r + 1];

  const s16x8 qv = *(const s16x8*)(q16 + (size_t)r * E_DIM + lane * 8);
  const float* __restrict__ biasp = att_bias + (size_t)h * NNZ_E;

  float m = -INFINITY, l = 0.f, accw = 0.f, a0 = 0.f, a1 = 0.f, a2 = 0.f;

  // full-head dot: 8 MACs + butterfly over the 8 lanes of the head group.
  auto dotk = [&](const s16x8 kv) -> float {
    float s = (float)qv[0] * (float)kv[0];
    s = fmaf((float)qv[1], (float)kv[1], s);
    s = fmaf((float)qv[2], (float)kv[2], s);
    s = fmaf((float)qv[3], (float)kv[3], s);
    s = fmaf((float)qv[4], (float)kv[4], s);
    s = fmaf((float)qv[5], (float)kv[5], s);
    s = fmaf((float)qv[6], (float)kv[6], s);
    s = fmaf((float)qv[7], (float)kv[7], s);
    s += __shfl_xor(s, 1);
    s += __shfl_xor(s, 2);
    s += __shfl_xor(s, 4);
    return s;
  };
  // online-softmax + weighted accumulation (first iter: m=-inf -> sc=0, ok).
  auto upd = [&](float logit, float dd, float c0, float c1, float c2) {
    const float w = (dd == 0.f) ? 0.f : 1.f / dd;
    const float nm = fmaxf(m, logit);
    const float sc = __expf(m - nm);
    const float p = __expf(logit - nm);
    m = nm;
    l = fmaf(l, sc, p);
    const float pw = p * w;
    accw = fmaf(accw, sc, pw);
    a0 = fmaf(a0, sc, pw * c0);
    a1 = fmaf(a1, sc, pw * c1);
    a2 = fmaf(a2, sc, pw * c2);
  };

  int e = start;
  for (; e + 2 <= end; e += 2) {
    const int g0 = ge[e], g1 = ge[e + 1];
    const s16x8 kv0 = *(const s16x8*)(k16 + (size_t)g0 * E_DIM + lane * 8);
    const s16x8 kv1 = *(const s16x8*)(k16 + (size_t)g1 * E_DIM + lane * 8);
    const int c0 = col_index[e], c1 = col_index[e + 1];
    const float dd0 = dist[e], dd1 = dist[e + 1];
    const float bb0 = biasp[e], bb1 = biasp[e + 1];
    const float cp00 = col_pos[c0 * 3 + 0];
    const float cp01 = col_pos[c0 * 3 + 1];
    const float cp02 = col_pos[c0 * 3 + 2];
    const float cp10 = col_pos[c1 * 3 + 0];
    const float cp11 = col_pos[c1 * 3 + 1];
    const float cp12 = col_pos[c1 * 3 + 2];
    const float s0 = dotk(kv0) * (1.f / 67108864.f) + bb0;
    const float s1 = dotk(kv1) * (1.f / 67108864.f) + bb1;
    upd(s0, dd0, cp00, cp01, cp02);
    upd(s1, dd1, cp10, cp11, cp12);
  }
  if (e < end) {
    const int g0 = ge[e];
    const s16x8 kv0 = *(const s16x8*)(k16 + (size_t)g0 * E_DIM + lane * 8);
    const int c0 = col_index[e];
    const float dd0 = dist[e];
    const float bb0 = biasp[e];
    const float cp00 = col_pos[c0 * 3 + 0];
    const float cp01 = col_pos[c0 * 3 + 1];
    const float cp02 = col_pos[c0 * 3 + 2];
    const float s0 = dotk(kv0) * (1.f / 67108864.f) + bb0;
    upd(s0, dd0, cp00, cp01, cp02);
  }

  if ((lane & 7) == 0) {
    const float invz = (l > 0.f) ? 1.f / l : 0.f;
    const float avg = accw * invz;
    const float v0 = a0 * invz - avg * pos[r * 3 + 0];
    const float v1 = a1 * invz - avg * pos[r * 3 + 1];
    const float v2 = a2 * invz - avg * pos[r * 3 + 2];
    const float nrm = sqrtf(v0 * v0 + v1 * v1 + v2 * v2);
    const float invn = 1.f / fmaxf(nrm, 1e-12f);
    float4 o;
    o.x = v0 * invn; o.y = v1 * invn; o.z = v2 * invn; o.w = avg;
    *(float4*)(out + (size_t)r * (H_HEADS * 4) + h * 4) = o;
  }
}

// ---------------------------------------------------------------------------
extern "C" void kernel_launch(void* const* d_in, const int* in_sizes, int n_in,
                              void* d_out, int out_size, void* d_ws,
                              size_t ws_size, hipStream_t stream) {
  const float* x        = (const float*)d_in[0];
  const int* row_index  = (const int*)d_in[1];
  const int* col_index  = (const int*)d_in[2];
  const int* to_col     = (const int*)d_in[3];
  const float* att_bias = (const float*)d_in[4];
  const float* dist     = (const float*)d_in[5];
  const float* pos      = (const float*)d_in[6];
  const float* col_pos  = (const float*)d_in[7];
  const float* q_w      = (const float*)d_in[8];
  const float* q_b      = (const float*)d_in[9];
  const float* k_w      = (const float*)d_in[10];
  const float* k_b      = (const float*)d_in[11];
  float* out = (float*)d_out;

  // ws: q16[N*E s16] | k16[N*E s16] | xs[N*1024 u16] | wq_s | wk_s
  //     | row_start[N+1] | ge[NNZ]
  short* q16 = (short*)d_ws;
  short* k16 = q16 + (size_t)N_NODES * E_DIM;
  unsigned short* xs = (unsigned short*)(k16 + (size_t)N_NODES * E_DIM);
  unsigned short* wq_s = xs + (size_t)N_NODES * 1024;
  unsigned short* wk_s = wq_s + 512 * 1024;
  int* row_start = (int*)(wk_s + 512 * 1024);
  int* ge = row_start + (N_NODES + 1);

  prep_small<<<512 + 16384 + NNZ_E / 256, 256, 0, stream>>>(
      x, q_w, k_w, row_index, col_index, to_col, wq_s, wk_s, xs, row_start, ge);

  gemm_mfma<<<2048, 256, 0, stream>>>(xs, wq_s, wk_s, q_b, k_b, q16, k16);

  row_fused<<<N_NODES / 4, 256, 0, stream>>>(q16, k16, row_start, ge, att_bias,
                                             col_index, dist, pos, col_pos,
                                             out);
}

// Round 5
// 261.560 us; speedup vs baseline: 1.3347x; 1.2249x over previous
//
#include <hip/hip_runtime.h>
#include <math.h>
#include <stdint.h>

#define N_NODES 32768
#define E_DIM   512
#define H_HEADS 8
#define D_HEAD  64
#define NNZ_E   524288

typedef __attribute__((ext_vector_type(4))) float f32x4;
typedef __attribute__((ext_vector_type(8))) _Float16 f16x8;  // 8 fp16 = 4 VGPRs
typedef __attribute__((ext_vector_type(8))) short s16x8;

// async 16B global->LDS (wave-uniform LDS base + lane*16)
__device__ __forceinline__ void async16(const void* g, void* l) {
  __builtin_amdgcn_global_load_lds(
      (const __attribute__((address_space(1))) void*)g,
      (__attribute__((address_space(3))) void*)l, 16, 0, 0);
}

// ---------------------------------------------------------------------------
// prep_small:
//   blocks [0,128)        : q_w -> fp16 wq_h [512][512]
//   blocks [128,256)      : k_w -> fp16 wk_h
//   blocks [256,8448)     : x   -> fp16 xs   [32768][512]
//   blocks [8448,10496)   : ge + CSR row_start
// fp16 (10 mantissa bits) replaces the 3-term split-bf16 scheme entirely:
// logit error from single-fp16 GEMM ~5e-4 (vs 0.0078 tolerance). Traffic
// drops 192->97 MB vs the bf16 hi|lo split pass.
// Each thread: 8 floats (2x float4 read) -> one 16B fp16 store.
// ---------------------------------------------------------------------------
__global__ __launch_bounds__(256) void prep_small(
    const float* __restrict__ x,
    const float* __restrict__ q_w, const float* __restrict__ k_w,
    const int* __restrict__ row_index, const int* __restrict__ col_index,
    const int* __restrict__ to_col,
    _Float16* __restrict__ wq_h, _Float16* __restrict__ wk_h,
    _Float16* __restrict__ xs,
    int* __restrict__ row_start, int* __restrict__ ge) {
  const int b = blockIdx.x;
  if (b < 8448) {
    const float* src;
    _Float16* dst;
    int t;
    if (b < 128)      { src = q_w; dst = wq_h; t = b * 256 + threadIdx.x; }
    else if (b < 256) { src = k_w; dst = wk_h; t = (b - 128) * 256 + threadIdx.x; }
    else              { src = x;   dst = xs;   t = (b - 256) * 256 + threadIdx.x; }
    const int r = t >> 6;            // 64 threads per 512-wide row
    const int c8 = (t & 63) << 3;    // 8 elements per thread
    const float4 v0 = *(const float4*)(src + (size_t)r * 512 + c8);
    const float4 v1 = *(const float4*)(src + (size_t)r * 512 + c8 + 4);
    f16x8 o;
    o[0] = (_Float16)v0.x; o[1] = (_Float16)v0.y;
    o[2] = (_Float16)v0.z; o[3] = (_Float16)v0.w;
    o[4] = (_Float16)v1.x; o[5] = (_Float16)v1.y;
    o[6] = (_Float16)v1.z; o[7] = (_Float16)v1.w;
    *(f16x8*)(dst + (size_t)r * 512 + c8) = o;
  } else {
    const int e = (b - 8448) * 256 + threadIdx.x;
    if (e < NNZ_E) {
      ge[e] = to_col[col_index[e]];
      const int r0 = row_index[e];
      const int r1 = (e + 1 < NNZ_E) ? row_index[e + 1] : N_NODES;
      if (e == 0)
        for (int r = 0; r <= r0; ++r) row_start[r] = 0;
      for (int r = r0 + 1; r <= r1; ++r) row_start[r] = e + 1;
    }
  }
}

// ---------------------------------------------------------------------------
// Single-term fp16 MFMA GEMM — round-2 sync structure (known-good), r12
// fragment maps, but 16 MFMA / 8 ds_read_b128 / 4 global_load_lds per
// K-step: exactly the m97-proven instruction mix (874 TF). FLOP total is
// 34.4 GF (3x less than the split-bf16 scheme) -> ~40 us floor.
// fp16 precision budget: logit err ~5e-4 << 0.0078 tolerance (10 mantissa
// bits; fp32 MFMA accumulate; |x|<~6, |w|<~0.3 all in fp16 normal range).
// XCD swizzle (b&7 = panel group) keeps the x panel HBM-once.
// Outputs int16: q16 = q*2048 (1/8 head-scale folded), k16 = k*4096;
// consumer divides by 2^26.
// ---------------------------------------------------------------------------
__global__ __launch_bounds__(256) void gemm_mfma(
    const _Float16* __restrict__ xs,   // [N][512] fp16
    const _Float16* __restrict__ wqh,  // [512][512] fp16
    const _Float16* __restrict__ wkh,
    const float* __restrict__ q_b, const float* __restrict__ k_b,
    short* __restrict__ q16, short* __restrict__ k16) {
  __shared__ _Float16 Ah[128 * 32];  // 8 KB each
  __shared__ _Float16 Bh[128 * 32];
  const int tid = threadIdx.x;
  const int w = tid >> 6;        // wave 0..3
  const int l = tid & 63;

  const int b = blockIdx.x;
  const int j = b >> 3;
  const int mb = (b & 7) * 32 + (j >> 3);
  const int c = j & 7;
  const bool is_q = ((c & 1) == 0);
  const int bm = mb * 128;
  const int bn = (c >> 1) * 128;

  const _Float16* __restrict__ wmat = is_q ? wqh : wkh;
  const float* __restrict__ bias = is_q ? q_b : k_b;
  short* __restrict__ outp = is_q ? q16 : k16;
  const float oscale = is_q ? 2048.f : 4096.f;

  const int wm = (w & 1) * 64;   // wave's m-quadrant
  const int wn = (w >> 1) * 64;  // wave's n-quadrant

  f32x4 acc[4][4];
#pragma unroll
  for (int i = 0; i < 4; ++i)
#pragma unroll
    for (int jj = 0; jj < 4; ++jj) acc[i][jj] = (f32x4){0.f, 0.f, 0.f, 0.f};

  // staging map (r7 swizzle): LDS chunk jx of row r holds global chunk
  // jx ^ ((r>>1)&3); lane l covers row w*16+(l>>2), chunk l&3.
  const int sr0 = w * 16 + (l >> 2);
  const int sr1 = sr0 + 64;
  const int sc = (((l & 3) ^ ((l >> 3) & 3)) << 3);
  // fragment map: lane wants row (base + fr), global K-chunk l>>4, stored at
  // chunk (l>>4) ^ ((fr>>1)&3).
  const int fr = l & 15;
  const int fcs = ((((l >> 4) ^ ((fr >> 1) & 3)) & 3) << 3);

  const _Float16* __restrict__ wa = wmat + (size_t)bn * 512;
  const _Float16* __restrict__ xa = xs + (size_t)bm * 512;

  for (int k0 = 0; k0 < 512; k0 += 32) {
    async16(xa + (size_t)sr0 * 512 + k0 + sc, Ah + w * 512);
    async16(xa + (size_t)sr1 * 512 + k0 + sc, Ah + (w + 4) * 512);
    async16(wa + (size_t)sr0 * 512 + k0 + sc, Bh + w * 512);
    async16(wa + (size_t)sr1 * 512 + k0 + sc, Bh + (w + 4) * 512);
    __syncthreads();

    f16x8 av[4], bv[4];
#pragma unroll
    for (int i = 0; i < 4; ++i)
      av[i] = *(const f16x8*)(Ah + (wm + i * 16 + fr) * 32 + fcs);
#pragma unroll
    for (int i = 0; i < 4; ++i)
      bv[i] = *(const f16x8*)(Bh + (wn + i * 16 + fr) * 32 + fcs);
#pragma unroll
    for (int i = 0; i < 4; ++i)
#pragma unroll
      for (int jj = 0; jj < 4; ++jj)
        acc[i][jj] = __builtin_amdgcn_mfma_f32_16x16x32_f16(
            av[i], bv[jj], acc[i][jj], 0, 0, 0);
    __syncthreads();
  }

  // epilogue: C/D layout col = l&15 (n), row = (l>>4)*4 + reg (m); int16 out
  const int cn = l & 15;
  const int cm4 = (l >> 4) * 4;
  float bvals[4];
#pragma unroll
  for (int jj = 0; jj < 4; ++jj) bvals[jj] = bias[bn + wn + jj * 16 + cn];
#pragma unroll
  for (int i = 0; i < 4; ++i) {
#pragma unroll
    for (int r = 0; r < 4; ++r) {
      const int m = bm + wm + i * 16 + cm4 + r;
      short* op = outp + (size_t)m * 512 + bn + wn + cn;
#pragma unroll
      for (int jj = 0; jj < 4; ++jj) {
        float v = (acc[i][jj][r] + bvals[jj]) * oscale;
        v = fmaxf(fminf(v, 32767.f), -32767.f);
        op[jj * 16] = (short)__float2int_rn(v);
      }
    }
  }
}

// ---------------------------------------------------------------------------
// row_fused: edge_logits + row_featurize in ONE kernel, CSR row-owned.
// One wave per row; q row loaded ONCE (lane l: q16[r][8l..8l+8], head h=l>>3).
// 4-edge unroll: all 4 k-row gathers + edge scalars issued before any dot —
// 4 independent 1KB gathers in flight per wave (was 2).
// Online-softmax runs identically in all 8 lanes of a head group (butterfly
// dot leaves the full logit in every lane), so no final cross-lane merge.
// ---------------------------------------------------------------------------
__global__ __launch_bounds__(256) void row_fused(
    const short* __restrict__ q16, const short* __restrict__ k16,
    const int* __restrict__ row_start, const int* __restrict__ ge,
    const float* __restrict__ att_bias, const int* __restrict__ col_index,
    const float* __restrict__ dist, const float* __restrict__ pos,
    const float* __restrict__ col_pos, float* __restrict__ out) {
  const int r = blockIdx.x * 4 + (threadIdx.x >> 6);
  const int lane = threadIdx.x & 63;
  const int h = lane >> 3;
  const int start = row_start[r];
  const int end = row_start[r + 1];

  const s16x8 qv = *(const s16x8*)(q16 + (size_t)r * E_DIM + lane * 8);
  const float* __restrict__ biasp = att_bias + (size_t)h * NNZ_E;

  float m = -INFINITY, l = 0.f, accw = 0.f, a0 = 0.f, a1 = 0.f, a2 = 0.f;

  auto dotk = [&](const s16x8 kv) -> float {
    float s = (float)qv[0] * (float)kv[0];
    s = fmaf((float)qv[1], (float)kv[1], s);
    s = fmaf((float)qv[2], (float)kv[2], s);
    s = fmaf((float)qv[3], (float)kv[3], s);
    s = fmaf((float)qv[4], (float)kv[4], s);
    s = fmaf((float)qv[5], (float)kv[5], s);
    s = fmaf((float)qv[6], (float)kv[6], s);
    s = fmaf((float)qv[7], (float)kv[7], s);
    s += __shfl_xor(s, 1);
    s += __shfl_xor(s, 2);
    s += __shfl_xor(s, 4);
    return s;
  };
  auto upd = [&](float logit, float dd, float c0, float c1, float c2) {
    const float w = (dd == 0.f) ? 0.f : 1.f / dd;
    const float nm = fmaxf(m, logit);
    const float sc = __expf(m - nm);
    const float p = __expf(logit - nm);
    m = nm;
    l = fmaf(l, sc, p);
    const float pw = p * w;
    accw = fmaf(accw, sc, pw);
    a0 = fmaf(a0, sc, pw * c0);
    a1 = fmaf(a1, sc, pw * c1);
    a2 = fmaf(a2, sc, pw * c2);
  };

  int e = start;
  for (; e + 4 <= end; e += 4) {
    int g[4], cc[4];
    float dd[4], bb[4], cp[4][3];
    s16x8 kv[4];
#pragma unroll
    for (int i = 0; i < 4; ++i) g[i] = ge[e + i];
#pragma unroll
    for (int i = 0; i < 4; ++i)
      kv[i] = *(const s16x8*)(k16 + (size_t)g[i] * E_DIM + lane * 8);
#pragma unroll
    for (int i = 0; i < 4; ++i) {
      cc[i] = col_index[e + i];
      dd[i] = dist[e + i];
      bb[i] = biasp[e + i];
    }
#pragma unroll
    for (int i = 0; i < 4; ++i) {
      cp[i][0] = col_pos[cc[i] * 3 + 0];
      cp[i][1] = col_pos[cc[i] * 3 + 1];
      cp[i][2] = col_pos[cc[i] * 3 + 2];
    }
    float s[4];
#pragma unroll
    for (int i = 0; i < 4; ++i)
      s[i] = dotk(kv[i]) * (1.f / 67108864.f) + bb[i];
#pragma unroll
    for (int i = 0; i < 4; ++i) upd(s[i], dd[i], cp[i][0], cp[i][1], cp[i][2]);
  }
  for (; e < end; ++e) {
    const int g0 = ge[e];
    const s16x8 kv0 = *(const s16x8*)(k16 + (size_t)g0 * E_DIM + lane * 8);
    const int c0 = col_index[e];
    const float dd0 = dist[e];
    const float bb0 = biasp[e];
    const float cp00 = col_pos[c0 * 3 + 0];
    const float cp01 = col_pos[c0 * 3 + 1];
    const float cp02 = col_pos[c0 * 3 + 2];
    const float s0 = dotk(kv0) * (1.f / 67108864.f) + bb0;
    upd(s0, dd0, cp00, cp01, cp02);
  }

  if ((lane & 7) == 0) {
    const float invz = (l > 0.f) ? 1.f / l : 0.f;
    const float avg = accw * invz;
    const float v0 = a0 * invz - avg * pos[r * 3 + 0];
    const float v1 = a1 * invz - avg * pos[r * 3 + 1];
    const float v2 = a2 * invz - avg * pos[r * 3 + 2];
    const float nrm = sqrtf(v0 * v0 + v1 * v1 + v2 * v2);
    const float invn = 1.f / fmaxf(nrm, 1e-12f);
    float4 o;
    o.x = v0 * invn; o.y = v1 * invn; o.z = v2 * invn; o.w = avg;
    *(float4*)(out + (size_t)r * (H_HEADS * 4) + h * 4) = o;
  }
}

// ---------------------------------------------------------------------------
extern "C" void kernel_launch(void* const* d_in, const int* in_sizes, int n_in,
                              void* d_out, int out_size, void* d_ws,
                              size_t ws_size, hipStream_t stream) {
  const float* x        = (const float*)d_in[0];
  const int* row_index  = (const int*)d_in[1];
  const int* col_index  = (const int*)d_in[2];
  const int* to_col     = (const int*)d_in[3];
  const float* att_bias = (const float*)d_in[4];
  const float* dist     = (const float*)d_in[5];
  const float* pos      = (const float*)d_in[6];
  const float* col_pos  = (const float*)d_in[7];
  const float* q_w      = (const float*)d_in[8];
  const float* q_b      = (const float*)d_in[9];
  const float* k_w      = (const float*)d_in[10];
  const float* k_b      = (const float*)d_in[11];
  float* out = (float*)d_out;

  // ws: q16[N*E s16] | k16[N*E s16] | xs[N*512 fp16] | wq_h | wk_h
  //     | row_start[N+1] | ge[NNZ]   (~99 MB)
  short* q16 = (short*)d_ws;
  short* k16 = q16 + (size_t)N_NODES * E_DIM;
  _Float16* xs = (_Float16*)(k16 + (size_t)N_NODES * E_DIM);
  _Float16* wq_h = xs + (size_t)N_NODES * 512;
  _Float16* wk_h = wq_h + 512 * 512;
  int* row_start = (int*)(wk_h + 512 * 512);
  int* ge = row_start + (N_NODES + 1);

  prep_small<<<8448 + NNZ_E / 256, 256, 0, stream>>>(
      x, q_w, k_w, row_index, col_index, to_col, wq_h, wk_h, xs, row_start, ge);

  gemm_mfma<<<2048, 256, 0, stream>>>(xs, wq_h, wk_h, q_b, k_b, q16, k16);

  row_fused<<<N_NODES / 4, 256, 0, stream>>>(q16, k16, row_start, ge, att_bias,
                                             col_index, dist, pos, col_pos,
                                             out);
}